// Round 5
// baseline (203.519 us; speedup 1.0000x reference)
//
#include <hip/hip_runtime.h>
#include <math.h>

using f32x4  = __attribute__((ext_vector_type(4))) float;
using bf16x8 = __attribute__((ext_vector_type(8))) short;

constexpr int kB = 4, kC = 256, kL = 2048, kH = 8;
constexpr float kQScale = 0.25505402264f;  // 1/sqrt(32) * log2(e)

__device__ __forceinline__ unsigned short f2bf(float f) {
    unsigned u = __builtin_bit_cast(unsigned, f);
    u += 0x7fffu + ((u >> 16) & 1u);
    return (unsigned short)(u >> 16);
}
__device__ __forceinline__ unsigned cvt_pk(float lo, float hi) {
    unsigned r;
    asm("v_cvt_pk_bf16_f32 %0, %1, %2" : "=v"(r) : "v"(lo), "v"(hi));
    return r;
}
__device__ __forceinline__ f32x4 mfma16(bf16x8 a, bf16x8 b, f32x4 c) {
    return __builtin_amdgcn_mfma_f32_16x16x32_bf16(a, b, c, 0, 0, 0);
}
__device__ __forceinline__ bf16x8 bc8(unsigned a, unsigned b, unsigned c, unsigned d) {
    return __builtin_bit_cast(bf16x8, make_uint4(a, b, c, d));
}

// ---------------------------------------------------------------------------
// fp32 -> bf16 for both weight matrices in one launch.
// ---------------------------------------------------------------------------
__global__ __launch_bounds__(256) void cvt_kernel(const float* __restrict__ qkvw,
                                                  const float* __restrict__ outw,
                                                  unsigned short* __restrict__ wq,
                                                  unsigned short* __restrict__ wo) {
    int i = blockIdx.x * 256 + threadIdx.x;  // 0..65535 float4s
    const float* s; unsigned short* d; int j;
    if (i < 49152) { s = qkvw; d = wq; j = i; }
    else           { s = outw; d = wo; j = i - 49152; }
    float4 v = ((const float4*)s)[j];
    ((uint2*)d)[j] = make_uint2(cvt_pk(v.x, v.y), cvt_pk(v.z, v.w));
}

// ---------------------------------------------------------------------------
// GroupNorm: one block per (b,group). Outputs hT bf16 [B][L][C].
// ---------------------------------------------------------------------------
__global__ __launch_bounds__(256) void gn_kernel(const float* __restrict__ x,
                                                 const float* __restrict__ gw,
                                                 const float* __restrict__ gb,
                                                 unsigned short* __restrict__ hT) {
    int b = blockIdx.x >> 5, g = blockIdx.x & 31;
    int t = threadIdx.x;
    const float* xp = x + ((size_t)b * kC + g * 8) * kL + 8 * t;

    float v[8][8];
    float s = 0.f, ss = 0.f;
#pragma unroll
    for (int c = 0; c < 8; ++c) {
        float4 a  = *(const float4*)(xp + (size_t)c * kL);
        float4 a2 = *(const float4*)(xp + (size_t)c * kL + 4);
        v[c][0]=a.x; v[c][1]=a.y; v[c][2]=a.z; v[c][3]=a.w;
        v[c][4]=a2.x; v[c][5]=a2.y; v[c][6]=a2.z; v[c][7]=a2.w;
        s  += (a.x+a.y)+(a.z+a.w)+(a2.x+a2.y)+(a2.z+a2.w);
        ss += a.x*a.x+a.y*a.y+a.z*a.z+a.w*a.w+a2.x*a2.x+a2.y*a2.y+a2.z*a2.z+a2.w*a2.w;
    }
#pragma unroll
    for (int off = 32; off; off >>= 1) {
        s  += __shfl_down(s, off);
        ss += __shfl_down(ss, off);
    }
    __shared__ float red[8];
    int wv = t >> 6;
    if ((t & 63) == 0) { red[wv] = s; red[4 + wv] = ss; }
    __syncthreads();
    s  = red[0] + red[1] + red[2] + red[3];
    ss = red[4] + red[5] + red[6] + red[7];
    float mean = s * (1.f / 16384.f);
    float var  = ss * (1.f / 16384.f) - mean * mean;
    float rstd = rsqrtf(var + 1e-5f);

    float wc[8], bc[8];
#pragma unroll
    for (int c = 0; c < 8; ++c) { wc[c] = gw[g*8+c] * rstd; bc[c] = gb[g*8+c]; }

    unsigned short* hp = hT + ((size_t)b * kL + 8 * t) * kC + g * 8;
#pragma unroll
    for (int j = 0; j < 8; ++j) {
        unsigned pk[4];
#pragma unroll
        for (int c2 = 0; c2 < 4; ++c2) {
            pk[c2] = cvt_pk((v[2*c2  ][j] - mean) * wc[2*c2  ] + bc[2*c2  ],
                            (v[2*c2+1][j] - mean) * wc[2*c2+1] + bc[2*c2+1]);
        }
        *(uint4*)(hp + (size_t)j * kC) = make_uint4(pk[0], pk[1], pk[2], pk[3]);
    }
}

// ---------------------------------------------------------------------------
// Merged QKV GEMM, W-in-registers. Block: o-tile 64 (wave=16 rows), n-tile 128.
// q,k stored transposed [B][H][L][32]; v stored [B][256][L].
// q pre-scaled by 1/sqrt(D)*log2(e), bias fused.
// ---------------------------------------------------------------------------
__device__ __forceinline__ void store_qk(unsigned short* __restrict__ base, size_t bh,
                                         int n, int d0, f32x4 acc,
                                         const float* bias4, float scale) {
    float v0 = (acc[0] + bias4[0]) * scale, v1 = (acc[1] + bias4[1]) * scale;
    float v2 = (acc[2] + bias4[2]) * scale, v3 = (acc[3] + bias4[3]) * scale;
    *(uint2*)(base + (bh * kL + n) * 32 + d0) = make_uint2(cvt_pk(v0, v1), cvt_pk(v2, v3));
}

__global__ __launch_bounds__(256) void qkv_gemm(const unsigned short* __restrict__ Wb,
                                                const unsigned short* __restrict__ hT,
                                                const float* __restrict__ qkvb,
                                                unsigned short* __restrict__ qT,
                                                unsigned short* __restrict__ kT,
                                                unsigned short* __restrict__ vbuf) {
    int t = threadIdx.x, wv = t >> 6, ll = t & 15, lg = (t >> 4) & 3;
    int n0 = blockIdx.x * 128, o0 = blockIdx.y * 64, b = blockIdx.z;
    int obase = o0 + wv * 16;
    const unsigned short* hb = hT + (size_t)b * kL * kC;

    bf16x8 wf[8];
#pragma unroll
    for (int k = 0; k < 8; ++k)
        wf[k] = *(const bf16x8*)(Wb + (size_t)(obase + ll) * 256 + 32 * k + 8 * lg);
    float bias[4];
#pragma unroll
    for (int r = 0; r < 4; ++r) bias[r] = qkvb[obase + 4 * lg + r];
    int mode = (obase < 256) ? 0 : (obase < 512 ? 1 : 2);
    int d0 = (obase & 31) + 4 * lg;

    for (int np = 0; np < 4; ++np) {
        f32x4 acc0 = {}, acc1 = {};
        int nA = n0 + np * 32 + ll, nB = nA + 16;
#pragma unroll
        for (int k = 0; k < 8; ++k) {
            bf16x8 h0 = *(const bf16x8*)(hb + (size_t)nA * 256 + 32 * k + 8 * lg);
            bf16x8 h1 = *(const bf16x8*)(hb + (size_t)nB * 256 + 32 * k + 8 * lg);
            acc0 = mfma16(wf[k], h0, acc0);
            acc1 = mfma16(wf[k], h1, acc1);
        }
        if (mode == 0) {
            size_t bh = (size_t)b * kH + (obase >> 5);
            store_qk(qT, bh, nA, d0, acc0, bias, kQScale);
            store_qk(qT, bh, nB, d0, acc1, bias, kQScale);
        } else if (mode == 1) {
            size_t bh = (size_t)b * kH + ((obase - 256) >> 5);
            store_qk(kT, bh, nA, d0, acc0, bias, 1.f);
            store_qk(kT, bh, nB, d0, acc1, bias, 1.f);
        } else {
#pragma unroll
            for (int r = 0; r < 4; ++r) {
                size_t row = (size_t)b * kC + (obase - 512) + 4 * lg + r;
                vbuf[row * kL + nA] = f2bf(acc0[r] + bias[r]);
                vbuf[row * kL + nB] = f2bf(acc1[r] + bias[r]);
            }
        }
    }
}

// ---------------------------------------------------------------------------
// Flash attention v5: no-max softmax (exp2 directly, logits bounded), 16 q/wave,
// 64-key tiles, manual register double-buffer (no copies), NO LDS:
// P B-fragment is lane-local because V is loaded with the matching permuted
// key->k-slot mapping: key(k=8g+e) = 32u + 16(e>>2) + 4g + (e&3).
// Grid 1024 blocks (4/CU, 16 waves/CU), XCD-swizzled.
// ---------------------------------------------------------------------------
__global__ __launch_bounds__(256, 4) void attn_kernel(const unsigned short* __restrict__ qT,
                                                      const unsigned short* __restrict__ kT,
                                                      const unsigned short* __restrict__ vbuf,
                                                      unsigned short* __restrict__ h2T) {
    int t = threadIdx.x, wv = t >> 6, ll = t & 15, g = (t >> 4) & 3;
    int j = blockIdx.x;
    int bid = (j & 7) * 128 + (j >> 3);   // 8 XCDs x 128 blocks; 4 heads per XCD
    int qt = bid & 31, bh = bid >> 5;     // qt 0..31, bh 0..31
    int b = bh >> 3, h = bh & 7;
    const unsigned short* qb = qT + (size_t)bh * kL * 32;
    const unsigned short* kb = kT + (size_t)bh * kL * 32;
    const unsigned short* vb = vbuf + ((size_t)b * kC + h * 32) * kL;
    int nq = qt * 64 + wv * 16;           // queries nq..nq+15

    bf16x8 qf = *(const bf16x8*)(qb + (size_t)(nq + ll) * 32 + 8 * g);
    f32x4 acc0 = {}, acc1 = {};
    float lsum = 0.f;
    const f32x4 zero = {0.f, 0.f, 0.f, 0.f};

    const int krow  = ll * 32 + 8 * g;          // per-lane K offset
    const int vrow0 = ll * kL + 4 * g;          // dj=0 per-lane V offset
    const int vrow1 = (16 + ll) * kL + 4 * g;   // dj=1

    bf16x8 ka0[4], ka1[4];
    uint2  va0[2][2][2], va1[2][2][2];          // [dj][u][half]

#define LOADKV(KA, VA, tt)                                                   \
    {                                                                        \
        int ko = ((tt) & 31) * 2048 + krow, vo = ((tt) & 31) * 64;           \
        KA[0] = *(const bf16x8*)(kb + ko);                                   \
        KA[1] = *(const bf16x8*)(kb + ko + 512);                             \
        KA[2] = *(const bf16x8*)(kb + ko + 1024);                            \
        KA[3] = *(const bf16x8*)(kb + ko + 1536);                            \
        VA[0][0][0] = *(const uint2*)(vb + vrow0 + vo);                      \
        VA[0][0][1] = *(const uint2*)(vb + vrow0 + vo + 16);                 \
        VA[0][1][0] = *(const uint2*)(vb + vrow0 + vo + 32);                 \
        VA[0][1][1] = *(const uint2*)(vb + vrow0 + vo + 48);                 \
        VA[1][0][0] = *(const uint2*)(vb + vrow1 + vo);                      \
        VA[1][0][1] = *(const uint2*)(vb + vrow1 + vo + 16);                 \
        VA[1][1][0] = *(const uint2*)(vb + vrow1 + vo + 32);                 \
        VA[1][1][1] = *(const uint2*)(vb + vrow1 + vo + 48);                 \
    }

#define EXPPACK(S, WA, WB)                                                   \
    {                                                                        \
        float p0 = __builtin_amdgcn_exp2f(S[0]);                             \
        float p1 = __builtin_amdgcn_exp2f(S[1]);                             \
        float p2 = __builtin_amdgcn_exp2f(S[2]);                             \
        float p3 = __builtin_amdgcn_exp2f(S[3]);                             \
        lsum += (p0 + p1) + (p2 + p3);                                       \
        WA = cvt_pk(p0, p1);                                                 \
        WB = cvt_pk(p2, p3);                                                 \
    }

#define TILE(KA, VA)                                                         \
    {                                                                        \
        __builtin_amdgcn_s_setprio(1);                                       \
        f32x4 s0 = mfma16(KA[0], qf, zero);                                  \
        f32x4 s1 = mfma16(KA[1], qf, zero);                                  \
        f32x4 s2 = mfma16(KA[2], qf, zero);                                  \
        f32x4 s3 = mfma16(KA[3], qf, zero);                                  \
        __builtin_amdgcn_s_setprio(0);                                       \
        unsigned w00, w01, w10, w11, w20, w21, w30, w31;                     \
        EXPPACK(s0, w00, w01) EXPPACK(s1, w10, w11)                          \
        EXPPACK(s2, w20, w21) EXPPACK(s3, w30, w31)                          \
        bf16x8 pb0 = bc8(w00, w01, w10, w11);                                \
        bf16x8 pb1 = bc8(w20, w21, w30, w31);                                \
        bf16x8 va00 = bc8(VA[0][0][0].x, VA[0][0][0].y, VA[0][0][1].x, VA[0][0][1].y); \
        bf16x8 va01 = bc8(VA[0][1][0].x, VA[0][1][0].y, VA[0][1][1].x, VA[0][1][1].y); \
        bf16x8 va10 = bc8(VA[1][0][0].x, VA[1][0][0].y, VA[1][0][1].x, VA[1][0][1].y); \
        bf16x8 va11 = bc8(VA[1][1][0].x, VA[1][1][0].y, VA[1][1][1].x, VA[1][1][1].y); \
        __builtin_amdgcn_s_setprio(1);                                       \
        acc0 = mfma16(va00, pb0, acc0);                                      \
        acc0 = mfma16(va01, pb1, acc0);                                      \
        acc1 = mfma16(va10, pb0, acc1);                                      \
        acc1 = mfma16(va11, pb1, acc1);                                      \
        __builtin_amdgcn_s_setprio(0);                                       \
    }

    LOADKV(ka0, va0, 0)
    for (int it = 0; it < 16; ++it) {
        LOADKV(ka1, va1, 2 * it + 1)
        TILE(ka0, va0)
        LOADKV(ka0, va0, 2 * it + 2)
        TILE(ka1, va1)
    }

    lsum += __shfl_xor(lsum, 16);
    lsum += __shfl_xor(lsum, 32);
    float inv = 1.f / lsum;
    unsigned short* ob = h2T + ((size_t)b * kL + nq + ll) * kC + h * 32;
    *(uint2*)(ob + 4 * g)      = make_uint2(cvt_pk(acc0[0] * inv, acc0[1] * inv),
                                            cvt_pk(acc0[2] * inv, acc0[3] * inv));
    *(uint2*)(ob + 16 + 4 * g) = make_uint2(cvt_pk(acc1[0] * inv, acc1[1] * inv),
                                            cvt_pk(acc1[2] * inv, acc1[3] * inv));
#undef LOADKV
#undef EXPPACK
#undef TILE
}

// ---------------------------------------------------------------------------
// OUT GEMM, W-in-registers. Block: o-tile 64 (wave=16), n-tile 64.
// out[o][n] = sum_c Wout[o][c] h2T[n][c] + bias + x, fp32 out.
// ---------------------------------------------------------------------------
__global__ __launch_bounds__(256) void out_gemm(const unsigned short* __restrict__ Wb,
                                                const unsigned short* __restrict__ h2T,
                                                const float* __restrict__ outb,
                                                const float* __restrict__ x,
                                                float* __restrict__ out) {
    int t = threadIdx.x, wv = t >> 6, ll = t & 15, lg = (t >> 4) & 3;
    int n0 = blockIdx.x * 64, o0 = blockIdx.y * 64, b = blockIdx.z;
    int obase = o0 + wv * 16;
    const unsigned short* hb = h2T + (size_t)b * kL * kC;

    bf16x8 wf[8];
#pragma unroll
    for (int k = 0; k < 8; ++k)
        wf[k] = *(const bf16x8*)(Wb + (size_t)(obase + ll) * 256 + 32 * k + 8 * lg);
    float bias[4];
#pragma unroll
    for (int r = 0; r < 4; ++r) bias[r] = outb[obase + 4 * lg + r];

    for (int np = 0; np < 2; ++np) {
        f32x4 acc0 = {}, acc1 = {};
        int nA = n0 + np * 32 + ll, nB = nA + 16;
#pragma unroll
        for (int k = 0; k < 8; ++k) {
            bf16x8 h0 = *(const bf16x8*)(hb + (size_t)nA * 256 + 32 * k + 8 * lg);
            bf16x8 h1 = *(const bf16x8*)(hb + (size_t)nB * 256 + 32 * k + 8 * lg);
            acc0 = mfma16(wf[k], h0, acc0);
            acc1 = mfma16(wf[k], h1, acc1);
        }
#pragma unroll
        for (int r = 0; r < 4; ++r) {
            size_t row = (size_t)b * kC + obase + 4 * lg + r;
            out[row * kL + nA] = acc0[r] + bias[r] + x[row * kL + nA];
            out[row * kL + nB] = acc1[r] + bias[r] + x[row * kL + nB];
        }
    }
}

// ---------------------------------------------------------------------------
extern "C" void kernel_launch(void* const* d_in, const int* in_sizes, int n_in,
                              void* d_out, int out_size, void* d_ws, size_t ws_size,
                              hipStream_t stream) {
    const float* x     = (const float*)d_in[0];
    const float* gn_w  = (const float*)d_in[1];
    const float* gn_b  = (const float*)d_in[2];
    const float* qkv_w = (const float*)d_in[3];
    const float* qkv_b = (const float*)d_in[4];
    const float* out_w = (const float*)d_in[5];
    const float* out_b = (const float*)d_in[6];
    float* out = (float*)d_out;

    char* ws = (char*)d_ws;
    const size_t MB = 1024 * 1024;
    unsigned short* hT   = (unsigned short*)(ws);             // 4 MB
    unsigned short* qT   = (unsigned short*)(ws + 4  * MB);   // 4 MB
    unsigned short* kT   = (unsigned short*)(ws + 8  * MB);   // 4 MB
    unsigned short* vbuf = (unsigned short*)(ws + 12 * MB);   // 4 MB
    unsigned short* h2T  = (unsigned short*)(ws + 16 * MB);   // 4 MB
    unsigned short* wqkv = (unsigned short*)(ws + 20 * MB);   // 384 KB
    unsigned short* wout = (unsigned short*)(ws + 20 * MB + 512 * 1024);

    cvt_kernel<<<dim3(256), 256, 0, stream>>>(qkv_w, out_w, wqkv, wout);
    gn_kernel<<<dim3(kB * 32), 256, 0, stream>>>(x, gn_w, gn_b, hT);
    qkv_gemm<<<dim3(16, 12, kB), 256, 0, stream>>>(wqkv, hT, qkv_b, qT, kT, vbuf);
    attn_kernel<<<dim3(1024), 256, 0, stream>>>(qT, kT, vbuf, h2T);
    out_gemm<<<dim3(32, 4, kB), 256, 0, stream>>>(wout, h2T, out_b, x, out);
}

// Round 6
// 136.124 us; speedup vs baseline: 1.4951x; 1.4951x over previous
//
#include <hip/hip_runtime.h>
#include <math.h>

using f32x4  = __attribute__((ext_vector_type(4))) float;
using bf16x8 = __attribute__((ext_vector_type(8))) short;

constexpr int kB = 4, kC = 256, kL = 2048, kH = 8;
constexpr float kQScale = 0.25505402264f;  // 1/sqrt(32) * log2(e)

__device__ __forceinline__ unsigned short f2bf(float f) {
    unsigned u = __builtin_bit_cast(unsigned, f);
    u += 0x7fffu + ((u >> 16) & 1u);
    return (unsigned short)(u >> 16);
}
__device__ __forceinline__ unsigned cvt_pk(float lo, float hi) {
    unsigned r;
    asm("v_cvt_pk_bf16_f32 %0, %1, %2" : "=v"(r) : "v"(lo), "v"(hi));
    return r;
}
__device__ __forceinline__ f32x4 mfma16(bf16x8 a, bf16x8 b, f32x4 c) {
    return __builtin_amdgcn_mfma_f32_16x16x32_bf16(a, b, c, 0, 0, 0);
}
__device__ __forceinline__ bf16x8 bc8(unsigned a, unsigned b, unsigned c, unsigned d) {
    return __builtin_bit_cast(bf16x8, make_uint4(a, b, c, d));
}

// ---------------------------------------------------------------------------
// fp32 -> bf16 for both weight matrices in one launch.
// ---------------------------------------------------------------------------
__global__ __launch_bounds__(256) void cvt_kernel(const float* __restrict__ qkvw,
                                                  const float* __restrict__ outw,
                                                  unsigned short* __restrict__ wq,
                                                  unsigned short* __restrict__ wo) {
    int i = blockIdx.x * 256 + threadIdx.x;  // 0..65535 float4s
    const float* s; unsigned short* d; int j;
    if (i < 49152) { s = qkvw; d = wq; j = i; }
    else           { s = outw; d = wo; j = i - 49152; }
    float4 v = ((const float4*)s)[j];
    ((uint2*)d)[j] = make_uint2(cvt_pk(v.x, v.y), cvt_pk(v.z, v.w));
}

// ---------------------------------------------------------------------------
// GroupNorm: one block per (b,group). Outputs hT bf16 [B][L][C].
// ---------------------------------------------------------------------------
__global__ __launch_bounds__(256) void gn_kernel(const float* __restrict__ x,
                                                 const float* __restrict__ gw,
                                                 const float* __restrict__ gb,
                                                 unsigned short* __restrict__ hT) {
    int b = blockIdx.x >> 5, g = blockIdx.x & 31;
    int t = threadIdx.x;
    const float* xp = x + ((size_t)b * kC + g * 8) * kL + 8 * t;

    float v[8][8];
    float s = 0.f, ss = 0.f;
#pragma unroll
    for (int c = 0; c < 8; ++c) {
        float4 a  = *(const float4*)(xp + (size_t)c * kL);
        float4 a2 = *(const float4*)(xp + (size_t)c * kL + 4);
        v[c][0]=a.x; v[c][1]=a.y; v[c][2]=a.z; v[c][3]=a.w;
        v[c][4]=a2.x; v[c][5]=a2.y; v[c][6]=a2.z; v[c][7]=a2.w;
        s  += (a.x+a.y)+(a.z+a.w)+(a2.x+a2.y)+(a2.z+a2.w);
        ss += a.x*a.x+a.y*a.y+a.z*a.z+a.w*a.w+a2.x*a2.x+a2.y*a2.y+a2.z*a2.z+a2.w*a2.w;
    }
#pragma unroll
    for (int off = 32; off; off >>= 1) {
        s  += __shfl_down(s, off);
        ss += __shfl_down(ss, off);
    }
    __shared__ float red[8];
    int wv = t >> 6;
    if ((t & 63) == 0) { red[wv] = s; red[4 + wv] = ss; }
    __syncthreads();
    s  = red[0] + red[1] + red[2] + red[3];
    ss = red[4] + red[5] + red[6] + red[7];
    float mean = s * (1.f / 16384.f);
    float var  = ss * (1.f / 16384.f) - mean * mean;
    float rstd = rsqrtf(var + 1e-5f);

    float wc[8], bc[8];
#pragma unroll
    for (int c = 0; c < 8; ++c) { wc[c] = gw[g*8+c] * rstd; bc[c] = gb[g*8+c]; }

    unsigned short* hp = hT + ((size_t)b * kL + 8 * t) * kC + g * 8;
#pragma unroll
    for (int j = 0; j < 8; ++j) {
        unsigned pk[4];
#pragma unroll
        for (int c2 = 0; c2 < 4; ++c2) {
            pk[c2] = cvt_pk((v[2*c2  ][j] - mean) * wc[2*c2  ] + bc[2*c2  ],
                            (v[2*c2+1][j] - mean) * wc[2*c2+1] + bc[2*c2+1]);
        }
        *(uint4*)(hp + (size_t)j * kC) = make_uint4(pk[0], pk[1], pk[2], pk[3]);
    }
}

// ---------------------------------------------------------------------------
// Merged QKV GEMM, W-in-registers. Block: o-tile 64 (wave=16 rows), n-tile 128.
// q,k stored transposed [B][H][L][32]; v stored [B][256][L].
// q pre-scaled by 1/sqrt(D)*log2(e), bias fused.
// ---------------------------------------------------------------------------
__device__ __forceinline__ void store_qk(unsigned short* __restrict__ base, size_t bh,
                                         int n, int d0, f32x4 acc,
                                         const float* bias4, float scale) {
    float v0 = (acc[0] + bias4[0]) * scale, v1 = (acc[1] + bias4[1]) * scale;
    float v2 = (acc[2] + bias4[2]) * scale, v3 = (acc[3] + bias4[3]) * scale;
    *(uint2*)(base + (bh * kL + n) * 32 + d0) = make_uint2(cvt_pk(v0, v1), cvt_pk(v2, v3));
}

__global__ __launch_bounds__(256) void qkv_gemm(const unsigned short* __restrict__ Wb,
                                                const unsigned short* __restrict__ hT,
                                                const float* __restrict__ qkvb,
                                                unsigned short* __restrict__ qT,
                                                unsigned short* __restrict__ kT,
                                                unsigned short* __restrict__ vbuf) {
    int t = threadIdx.x, wv = t >> 6, ll = t & 15, lg = (t >> 4) & 3;
    int n0 = blockIdx.x * 128, o0 = blockIdx.y * 64, b = blockIdx.z;
    int obase = o0 + wv * 16;
    const unsigned short* hb = hT + (size_t)b * kL * kC;

    bf16x8 wf[8];
#pragma unroll
    for (int k = 0; k < 8; ++k)
        wf[k] = *(const bf16x8*)(Wb + (size_t)(obase + ll) * 256 + 32 * k + 8 * lg);
    float bias[4];
#pragma unroll
    for (int r = 0; r < 4; ++r) bias[r] = qkvb[obase + 4 * lg + r];
    int mode = (obase < 256) ? 0 : (obase < 512 ? 1 : 2);
    int d0 = (obase & 31) + 4 * lg;

    for (int np = 0; np < 4; ++np) {
        f32x4 acc0 = {}, acc1 = {};
        int nA = n0 + np * 32 + ll, nB = nA + 16;
#pragma unroll
        for (int k = 0; k < 8; ++k) {
            bf16x8 h0 = *(const bf16x8*)(hb + (size_t)nA * 256 + 32 * k + 8 * lg);
            bf16x8 h1 = *(const bf16x8*)(hb + (size_t)nB * 256 + 32 * k + 8 * lg);
            acc0 = mfma16(wf[k], h0, acc0);
            acc1 = mfma16(wf[k], h1, acc1);
        }
        if (mode == 0) {
            size_t bh = (size_t)b * kH + (obase >> 5);
            store_qk(qT, bh, nA, d0, acc0, bias, kQScale);
            store_qk(qT, bh, nB, d0, acc1, bias, kQScale);
        } else if (mode == 1) {
            size_t bh = (size_t)b * kH + ((obase - 256) >> 5);
            store_qk(kT, bh, nA, d0, acc0, bias, 1.f);
            store_qk(kT, bh, nB, d0, acc1, bias, 1.f);
        } else {
#pragma unroll
            for (int r = 0; r < 4; ++r) {
                size_t row = (size_t)b * kC + (obase - 512) + 4 * lg + r;
                vbuf[row * kL + nA] = f2bf(acc0[r] + bias[r]);
                vbuf[row * kL + nB] = f2bf(acc1[r] + bias[r]);
            }
        }
    }
}

// ---------------------------------------------------------------------------
// Flash attention v6: no-max softmax (exp2 direct, logits bounded), 32 q/wave,
// 64-key tiles, round-4-style register double buffer (explicit copies), NO LDS
// in the loop: P B-fragment is lane-local via permuted key<->k-slot mapping
// key(k=8g+e) = 32u + 16(e>>2) + 4g + (e&3); V loaded with matching layout.
// Split-K: waves 0/1 do keys 0..1023 for queries [0..32)/[32..64), waves 2/3
// do keys 1024..2047; partials combine by plain ADD (no-max softmax) through
// LDS at the end. Grid 1024 (4 blocks/CU), XCD-swizzled.
// ---------------------------------------------------------------------------
__global__ __launch_bounds__(256, 4) void attn_kernel(const unsigned short* __restrict__ qT,
                                                      const unsigned short* __restrict__ kT,
                                                      const unsigned short* __restrict__ vbuf,
                                                      unsigned short* __restrict__ h2T) {
    __shared__ float comb[2][18][64];
    int t = threadIdx.x, wv = t >> 6, ll = t & 15, g = (t >> 4) & 3;
    int lane = t & 63;
    int j = blockIdx.x;
    int bid = (j & 7) * 128 + (j >> 3);   // XCD swizzle: 8 XCDs x 128 blocks
    int qt = bid & 31, bh = bid >> 5;     // qt 0..31 (64q tiles), bh 0..31
    int b = bh >> 3, h = bh & 7;
    const unsigned short* qb = qT + (size_t)bh * kL * 32;
    const unsigned short* kb = kT + (size_t)bh * kL * 32;
    const unsigned short* vb = vbuf + ((size_t)b * kC + h * 32) * kL;
    int nbase = qt * 64 + (wv & 1) * 32;  // 32 queries per wave
    int kstart = (wv >> 1) * 1024;        // split-K half

    bf16x8 qf[2];
#pragma unroll
    for (int nj = 0; nj < 2; ++nj)
        qf[nj] = *(const bf16x8*)(qb + (size_t)(nbase + 16 * nj + ll) * 32 + 8 * g);

    f32x4 acc[2][2] = {};                 // [nj][dj]
    float lsum[2] = {0.f, 0.f};
    const f32x4 zero = {0.f, 0.f, 0.f, 0.f};

    const int koff  = ll * 32 + 8 * g;    // K: row=key stride 32
    const int voff0 = ll * kL + 4 * g;    // V: d=ll row
    const int voff1 = (16 + ll) * kL + 4 * g;

    // prefetch tile 0 of this wave's K-half
    bf16x8 ka[4];
    uint2  va[2][2][2];                   // [dj][u][half]
#pragma unroll
    for (int mj = 0; mj < 4; ++mj)
        ka[mj] = *(const bf16x8*)(kb + (size_t)kstart * 32 + mj * 512 + koff);
#pragma unroll
    for (int u = 0; u < 2; ++u)
#pragma unroll
        for (int hf = 0; hf < 2; ++hf) {
            va[0][u][hf] = *(const uint2*)(vb + voff0 + kstart + 32 * u + 16 * hf);
            va[1][u][hf] = *(const uint2*)(vb + voff1 + kstart + 32 * u + 16 * hf);
        }

#pragma unroll 2
    for (int it = 0; it < 16; ++it) {
        int mn = kstart + ((it * 64 + 64) & 1023);  // next tile (wraps on last)
        bf16x8 nka[4];
        uint2  nva[2][2][2];
#pragma unroll
        for (int mj = 0; mj < 4; ++mj)
            nka[mj] = *(const bf16x8*)(kb + (size_t)mn * 32 + mj * 512 + koff);
#pragma unroll
        for (int u = 0; u < 2; ++u)
#pragma unroll
            for (int hf = 0; hf < 2; ++hf) {
                nva[0][u][hf] = *(const uint2*)(vb + voff0 + mn + 32 * u + 16 * hf);
                nva[1][u][hf] = *(const uint2*)(vb + voff1 + mn + 32 * u + 16 * hf);
            }

        // QK^T (swapped): s[mj][nj] -> keys 16mj+4g+r, query 16nj+ll
        f32x4 s[4][2];
        __builtin_amdgcn_s_setprio(1);
#pragma unroll
        for (int mj = 0; mj < 4; ++mj)
#pragma unroll
            for (int nj = 0; nj < 2; ++nj)
                s[mj][nj] = mfma16(ka[mj], qf[nj], zero);
        __builtin_amdgcn_s_setprio(0);

        // exp2 + pack: lane-local P fragments
        unsigned w[4][2][2];
#pragma unroll
        for (int mj = 0; mj < 4; ++mj)
#pragma unroll
            for (int nj = 0; nj < 2; ++nj) {
                float p0 = __builtin_amdgcn_exp2f(s[mj][nj][0]);
                float p1 = __builtin_amdgcn_exp2f(s[mj][nj][1]);
                float p2 = __builtin_amdgcn_exp2f(s[mj][nj][2]);
                float p3 = __builtin_amdgcn_exp2f(s[mj][nj][3]);
                lsum[nj] += (p0 + p1) + (p2 + p3);
                w[mj][nj][0] = cvt_pk(p0, p1);
                w[mj][nj][1] = cvt_pk(p2, p3);
            }

        __builtin_amdgcn_s_setprio(1);
#pragma unroll
        for (int u = 0; u < 2; ++u) {
#pragma unroll
            for (int dj = 0; dj < 2; ++dj) {
                bf16x8 vfr = bc8(va[dj][u][0].x, va[dj][u][0].y,
                                 va[dj][u][1].x, va[dj][u][1].y);
#pragma unroll
                for (int nj = 0; nj < 2; ++nj) {
                    bf16x8 pb = bc8(w[2*u][nj][0], w[2*u][nj][1],
                                    w[2*u+1][nj][0], w[2*u+1][nj][1]);
                    acc[nj][dj] = mfma16(vfr, pb, acc[nj][dj]);
                }
            }
        }
        __builtin_amdgcn_s_setprio(0);

#pragma unroll
        for (int mj = 0; mj < 4; ++mj) ka[mj] = nka[mj];
#pragma unroll
        for (int dj = 0; dj < 2; ++dj)
#pragma unroll
            for (int u = 0; u < 2; ++u)
#pragma unroll
                for (int hf = 0; hf < 2; ++hf) va[dj][u][hf] = nva[dj][u][hf];
    }

    // split-K combine: waves 2/3 dump partials; waves 0/1 add + finalize.
    if (wv >= 2) {
        int sidx = wv - 2;
#pragma unroll
        for (int nj = 0; nj < 2; ++nj)
#pragma unroll
            for (int dj = 0; dj < 2; ++dj)
#pragma unroll
                for (int r = 0; r < 4; ++r)
                    comb[sidx][nj * 8 + dj * 4 + r][lane] = acc[nj][dj][r];
        comb[sidx][16][lane] = lsum[0];
        comb[sidx][17][lane] = lsum[1];
    }
    __syncthreads();
    if (wv < 2) {
#pragma unroll
        for (int nj = 0; nj < 2; ++nj)
#pragma unroll
            for (int dj = 0; dj < 2; ++dj)
#pragma unroll
                for (int r = 0; r < 4; ++r)
                    acc[nj][dj][r] += comb[wv][nj * 8 + dj * 4 + r][lane];
        lsum[0] += comb[wv][16][lane];
        lsum[1] += comb[wv][17][lane];

#pragma unroll
        for (int nj = 0; nj < 2; ++nj) {
            lsum[nj] += __shfl_xor(lsum[nj], 16);
            lsum[nj] += __shfl_xor(lsum[nj], 32);
            float inv = 1.f / lsum[nj];
            unsigned short* ob = h2T + ((size_t)b * kL + nbase + 16 * nj + ll) * kC + h * 32;
#pragma unroll
            for (int dj = 0; dj < 2; ++dj) {
                *(uint2*)(ob + 16 * dj + 4 * g) =
                    make_uint2(cvt_pk(acc[nj][dj][0] * inv, acc[nj][dj][1] * inv),
                               cvt_pk(acc[nj][dj][2] * inv, acc[nj][dj][3] * inv));
            }
        }
    }
}

// ---------------------------------------------------------------------------
// OUT GEMM, W-in-registers. Block: o-tile 64 (wave=16), n-tile 64.
// out[o][n] = sum_c Wout[o][c] h2T[n][c] + bias + x, fp32 out.
// ---------------------------------------------------------------------------
__global__ __launch_bounds__(256) void out_gemm(const unsigned short* __restrict__ Wb,
                                                const unsigned short* __restrict__ h2T,
                                                const float* __restrict__ outb,
                                                const float* __restrict__ x,
                                                float* __restrict__ out) {
    int t = threadIdx.x, wv = t >> 6, ll = t & 15, lg = (t >> 4) & 3;
    int n0 = blockIdx.x * 64, o0 = blockIdx.y * 64, b = blockIdx.z;
    int obase = o0 + wv * 16;
    const unsigned short* hb = h2T + (size_t)b * kL * kC;

    bf16x8 wf[8];
#pragma unroll
    for (int k = 0; k < 8; ++k)
        wf[k] = *(const bf16x8*)(Wb + (size_t)(obase + ll) * 256 + 32 * k + 8 * lg);
    float bias[4];
#pragma unroll
    for (int r = 0; r < 4; ++r) bias[r] = outb[obase + 4 * lg + r];

    for (int np = 0; np < 2; ++np) {
        f32x4 acc0 = {}, acc1 = {};
        int nA = n0 + np * 32 + ll, nB = nA + 16;
#pragma unroll
        for (int k = 0; k < 8; ++k) {
            bf16x8 h0 = *(const bf16x8*)(hb + (size_t)nA * 256 + 32 * k + 8 * lg);
            bf16x8 h1 = *(const bf16x8*)(hb + (size_t)nB * 256 + 32 * k + 8 * lg);
            acc0 = mfma16(wf[k], h0, acc0);
            acc1 = mfma16(wf[k], h1, acc1);
        }
#pragma unroll
        for (int r = 0; r < 4; ++r) {
            size_t row = (size_t)b * kC + obase + 4 * lg + r;
            out[row * kL + nA] = acc0[r] + bias[r] + x[row * kL + nA];
            out[row * kL + nB] = acc1[r] + bias[r] + x[row * kL + nB];
        }
    }
}

// ---------------------------------------------------------------------------
extern "C" void kernel_launch(void* const* d_in, const int* in_sizes, int n_in,
                              void* d_out, int out_size, void* d_ws, size_t ws_size,
                              hipStream_t stream) {
    const float* x     = (const float*)d_in[0];
    const float* gn_w  = (const float*)d_in[1];
    const float* gn_b  = (const float*)d_in[2];
    const float* qkv_w = (const float*)d_in[3];
    const float* qkv_b = (const float*)d_in[4];
    const float* out_w = (const float*)d_in[5];
    const float* out_b = (const float*)d_in[6];
    float* out = (float*)d_out;

    char* ws = (char*)d_ws;
    const size_t MB = 1024 * 1024;
    unsigned short* hT   = (unsigned short*)(ws);             // 4 MB
    unsigned short* qT   = (unsigned short*)(ws + 4  * MB);   // 4 MB
    unsigned short* kT   = (unsigned short*)(ws + 8  * MB);   // 4 MB
    unsigned short* vbuf = (unsigned short*)(ws + 12 * MB);   // 4 MB
    unsigned short* h2T  = (unsigned short*)(ws + 16 * MB);   // 4 MB
    unsigned short* wqkv = (unsigned short*)(ws + 20 * MB);   // 384 KB
    unsigned short* wout = (unsigned short*)(ws + 20 * MB + 512 * 1024);

    cvt_kernel<<<dim3(256), 256, 0, stream>>>(qkv_w, out_w, wqkv, wout);
    gn_kernel<<<dim3(kB * 32), 256, 0, stream>>>(x, gn_w, gn_b, hT);
    qkv_gemm<<<dim3(16, 12, kB), 256, 0, stream>>>(wqkv, hT, qkv_b, qT, kT, vbuf);
    attn_kernel<<<dim3(1024), 256, 0, stream>>>(qT, kT, vbuf, h2T);
    out_gemm<<<dim3(32, 4, kB), 256, 0, stream>>>(wout, h2T, out_b, x, out);
}